// Round 10
// baseline (185.831 us; speedup 1.0000x reference)
//
#include <hip/hip_runtime.h>

#define THREADS 256
#define NS 2
typedef float v2f __attribute__((ext_vector_type(2)));

// tanh(x) = 1 - 2/(exp(2x)+1), pk-packed pair: 3 pk VALU + 4 TRANS
__device__ __forceinline__ v2f tanh2(v2f x) {
    v2f xs = x * 2.885390081777927f;                // 2*log2(e)
    v2f e  = { __builtin_amdgcn_exp2f(xs.x),
               __builtin_amdgcn_exp2f(xs.y) };
    v2f ep = e + 1.0f;
    v2f r  = { __builtin_amdgcn_rcpf(ep.x),
               __builtin_amdgcn_rcpf(ep.y) };
    return (v2f){-2.0f, -2.0f} * r + 1.0f;
}

// NS samples at once: y[s][j] = tanh(b[j] + sum_k x[s][k]*W[k][j])
// Interleaving the two samples doubles within-wave ILP (fills dependency bubbles).
template<int IN, int OUT>
__device__ __forceinline__ void dense(const float (&x)[NS][16], float (&y)[NS][16],
                                      const float* __restrict__ W,
                                      const float* __restrict__ b) {
#pragma unroll
    for (int j = 0; j < OUT; j += 2) {
        v2f acc[NS];
#pragma unroll
        for (int s = 0; s < NS; ++s) acc[s] = (v2f){ b[j], b[j + 1] };
#pragma unroll
        for (int k = 0; k < IN; ++k) {
            v2f w = { W[k * OUT + j], W[k * OUT + j + 1] };
#pragma unroll
            for (int s = 0; s < NS; ++s) acc[s] += w * x[s][k];
        }
#pragma unroll
        for (int s = 0; s < NS; ++s) {
            v2f t = tanh2(acc[s]);
            y[s][j] = t.x; y[s][j + 1] = t.y;
        }
    }
}

__global__ __launch_bounds__(THREADS) void qcnn_fused(
        const float* __restrict__ inputs,
        const float* __restrict__ W_fm, const float* __restrict__ b_fm,
        const float* __restrict__ W1,  const float* __restrict__ b1,
        const float* __restrict__ Wp1, const float* __restrict__ bp1,
        const float* __restrict__ W2,  const float* __restrict__ b2,
        const float* __restrict__ Wp2, const float* __restrict__ bp2,
        const float* __restrict__ W3,  const float* __restrict__ b3,
        const float* __restrict__ protos,
        const float* __restrict__ Wh,  const float* __restrict__ bh,
        float* __restrict__ out, int B) {
    const int t0 = blockIdx.x * THREADS + threadIdx.x;
    const int T  = gridDim.x * THREADS;

    int  sidx[NS];
    bool valid[NS];
#pragma unroll
    for (int s = 0; s < NS; ++s) {
        sidx[s]  = t0 + s * T;          // both indices coalesced per instruction
        valid[s] = sidx[s] < B;
    }

    float xa[NS][16], xb[NS][16];
#pragma unroll
    for (int s = 0; s < NS; ++s) {
        int si = valid[s] ? sidx[s] : 0;
        const float4* in4 = reinterpret_cast<const float4*>(inputs) + (size_t)si * 2;
        float4 v0 = in4[0], v1 = in4[1];
        xa[s][0] = v0.x; xa[s][1] = v0.y; xa[s][2] = v0.z; xa[s][3] = v0.w;
        xa[s][4] = v1.x; xa[s][5] = v1.y; xa[s][6] = v1.z; xa[s][7] = v1.w;
    }

    dense<8, 16>(xa, xb, W_fm, b_fm);  // feature_map
    dense<16, 16>(xb, xa, W1, b1);     // conv1
    dense<16, 12>(xa, xb, Wp1, bp1);   // pool1
    dense<12, 8>(xb, xa, W2, b2);      // conv2
    dense<8, 4>(xa, xb, Wp2, bp2);     // pool2
    dense<4, 4>(xb, xa, W3, b3);       // conv3 -> xa[s][0..3]

#pragma unroll
    for (int s = 0; s < NS; ++s) {
        v2f ha = { bh[0], 0.0f };
        ha += (v2f){ xa[s][0], xa[s][1] } * (v2f){ Wh[0], Wh[1] };
        ha += (v2f){ xa[s][2], xa[s][3] } * (v2f){ Wh[2], Wh[3] };
        float acc = ha.x + ha.y;

#pragma unroll
        for (int j = 0; j < 10; j += 2) {
            v2f d2 = { 0.0f, 0.0f };
#pragma unroll
            for (int k = 0; k < 4; ++k) {
                v2f p = { protos[j * 4 + k], protos[(j + 1) * 4 + k] };
                v2f d = (v2f){ xa[s][k], xa[s][k] } - p;
                d2 += d * d;
            }
            v2f d2s = d2 * -1.4426950408889634f;        // -log2e
            float kf0 = __builtin_amdgcn_exp2f(d2s.x);  // exp(-d2)
            float kf1 = __builtin_amdgcn_exp2f(d2s.y);
            acc = fmaf(kf0, Wh[4 + j], acc);
            acc = fmaf(kf1, Wh[5 + j], acc);
        }
        float e = __builtin_amdgcn_exp2f(acc * -1.4426950408889634f);
        if (valid[s]) out[sidx[s]] = __builtin_amdgcn_rcpf(1.0f + e);
    }
}

extern "C" void kernel_launch(void* const* d_in, const int* in_sizes, int n_in,
                              void* d_out, int out_size, void* d_ws, size_t ws_size,
                              hipStream_t stream) {
    const float* inputs = (const float*)d_in[0];
    float* out = (float*)d_out;
    const int B = in_sizes[0] / 8;
    const int blocks = (B + THREADS * NS - 1) / (THREADS * NS);
    qcnn_fused<<<blocks, THREADS, 0, stream>>>(
        inputs,
        (const float*)d_in[1],  (const float*)d_in[2],
        (const float*)d_in[3],  (const float*)d_in[4],
        (const float*)d_in[5],  (const float*)d_in[6],
        (const float*)d_in[7],  (const float*)d_in[8],
        (const float*)d_in[9],  (const float*)d_in[10],
        (const float*)d_in[11], (const float*)d_in[12],
        (const float*)d_in[13],
        (const float*)d_in[14], (const float*)d_in[15],
        out, B);
}